// Round 1
// 645.425 us; speedup vs baseline: 1.0546x; 1.0546x over previous
//
#include <hip/hip_runtime.h>
#include <stdint.h>

#define DM 1024
#define DF 4096
#define NE 8
#define NTOK 8192   // B*S = 4*2048
#define MT_LAUNCH 72  // >= max total m-tiles (71), divisible by swizzle group G=8

typedef __attribute__((ext_vector_type(8))) short short8;
typedef __attribute__((ext_vector_type(8))) unsigned short ushort8v;
typedef __attribute__((ext_vector_type(4))) float floatx4;

__device__ inline unsigned short f2bf(float f) {
    union { float f; unsigned u; } v; v.f = f;
    unsigned u = v.u;
    u += 0x7fffu + ((u >> 16) & 1u);   // round-to-nearest-even
    return (unsigned short)(u >> 16);
}

#define GLDS(g, l) __builtin_amdgcn_global_load_lds( \
    (const __attribute__((address_space(1))) void*)(g), \
    (__attribute__((address_space(3))) void*)(l), 16, 0, 0)

// ---------------- gating: one wave per token, fp64 accumulation, no atomics ----------------
// fused: also emits the bf16 copy of x (saves a separate convert_x pass over 33.5 MB)
__global__ void gate_kernel(const float* __restrict__ x, const float* __restrict__ gw,
                            const float* __restrict__ gb, int* __restrict__ top1,
                            unsigned short* __restrict__ xb) {
    int t = blockIdx.x;
    int lane = threadIdx.x;            // 64 threads
    const float* xr = x + (size_t)t * DM;
    unsigned short* xbr = xb + (size_t)t * DM;
    double acc[NE];
#pragma unroll
    for (int e = 0; e < NE; ++e) acc[e] = 0.0;
    for (int j = 0; j < DM / 64; ++j) {
        int d = j * 64 + lane;
        float xf = xr[d];
        xbr[d] = f2bf(xf);
        double xv = (double)xf;
        const float* g = gw + (size_t)d * NE;
#pragma unroll
        for (int e = 0; e < NE; ++e) acc[e] = fma(xv, (double)g[e], acc[e]);
    }
#pragma unroll
    for (int e = 0; e < NE; ++e) {
        for (int off = 32; off > 0; off >>= 1)
            acc[e] += __shfl_down(acc[e], off, 64);
    }
    if (lane == 0) {
        int best = 0;
        double bv = acc[0] + (double)gb[0];
        for (int e = 1; e < NE; ++e) {
            double v = acc[e] + (double)gb[e];
            if (v > bv) { bv = v; best = e; }   // strict > == first-max (jnp.argmax)
        }
        top1[t] = best;
    }
}

// ctrl ints: [0..7] counts, [8..16] offsets (+total), [17..24] cursors, [25] ntiles,
//            [32+3i..] tile table: (expert, compacted rowbase, rows)
__global__ void count_kernel(const int* __restrict__ top1, int* __restrict__ ctrl) {
    int t = blockIdx.x * 256 + threadIdx.x;
    int e = top1[t];
    int lane = threadIdx.x & 63;
#pragma unroll
    for (int ex = 0; ex < NE; ++ex) {
        unsigned long long m = __ballot(e == ex);
        if (m != 0ull && lane == (__ffsll((long long)m) - 1))
            atomicAdd(&ctrl[ex], __popcll(m));
    }
}

__global__ void prefix_kernel(int* ctrl) {
    if (threadIdx.x == 0) {
        int s = 0, t = 0;
        for (int e = 0; e < NE; ++e) {
            int cnt = ctrl[e];
            ctrl[8 + e] = s; ctrl[17 + e] = s;
            for (int m = 0; m * 128 < cnt; ++m) {
                ctrl[32 + 3 * t] = e;
                ctrl[33 + 3 * t] = s + m * 128;
                int rr = cnt - m * 128;
                ctrl[34 + 3 * t] = rr < 128 ? rr : 128;
                ++t;
            }
            s += cnt;
        }
        ctrl[16] = s;
        ctrl[25] = t;
    }
}

__global__ void scatter_kernel(const int* __restrict__ top1, int* __restrict__ ctrl,
                               int* __restrict__ perm) {
    int t = blockIdx.x * 256 + threadIdx.x;
    int e = top1[t];
    int lane = threadIdx.x & 63;
#pragma unroll
    for (int ex = 0; ex < NE; ++ex) {
        unsigned long long m = __ballot(e == ex);
        if (m == 0ull) continue;
        int leader = __ffsll((long long)m) - 1;
        int base = 0;
        if (lane == leader) base = atomicAdd(&ctrl[17 + ex], __popcll(m));
        base = __shfl(base, leader, 64);
        if (e == ex) {
            int pos = __popcll(m & ((1ull << lane) - 1ull));
            perm[base + pos] = t;   // compacted position -> token id
        }
    }
}

// -------- tiled transpose + convert: src [E][R][C] f32 -> dst [E][C][R] bf16 --------
__global__ void transpose_bf16(const float* __restrict__ src, unsigned short* __restrict__ dst,
                               int R, int C) {
    __shared__ float tile[64][65];
    int tilesR = R >> 6, tilesC = C >> 6;
    int bid = blockIdx.x;
    int e = bid / (tilesR * tilesC);
    int rem = bid % (tilesR * tilesC);
    int tr = rem / tilesC, tc = rem % tilesC;
    const float* s = src + (size_t)e * R * C + (size_t)(tr * 64) * C + tc * 64;
    unsigned short* d = dst + (size_t)e * R * C + (size_t)(tc * 64) * R + tr * 64;
    int tid = threadIdx.x;
#pragma unroll
    for (int i = 0; i < 4; ++i) {
        int idx = i * 256 + tid;          // 0..1023
        int r = idx >> 4, c4 = (idx & 15) * 4;
        float4 v = *(const float4*)(s + (size_t)r * C + c4);
        tile[r][c4 + 0] = v.x; tile[r][c4 + 1] = v.y;
        tile[r][c4 + 2] = v.z; tile[r][c4 + 3] = v.w;
    }
    __syncthreads();
#pragma unroll
    for (int i = 0; i < 2; ++i) {
        int idx = i * 256 + tid;          // 0..511
        int c = idx >> 3, r8 = (idx & 7) * 8;
        ushort8v o;
#pragma unroll
        for (int j = 0; j < 8; ++j) o[j] = f2bf(tile[r8 + j][c]);
        *(ushort8v*)(d + (size_t)c * R + r8) = o;
    }
}

// ---------------- MFMA GEMM over the m-tile table, XOR-swizzled LDS ----------------
// LDS layout: row r's k-chunk gk (8 bf16 = 16B) lives at slot s = gk ^ (r&7).
// Staging: GLDS global addr is per-lane, so lane fetches chunk (slot ^ (r&7)); LDS dest stays
// contiguous (wave-uniform base + lane*16). Fragment ds_read_b128: addr = r*128B + s*16B ->
// banks 4s..4s+3, s a permutation of 0..7 over the quad's 16 lanes -> 2-way (free).
// NEW vs prev round: (a) double-buffered LDS + stage(t+1)-before-compute(t), one
// __syncthreads per K-step (T3-minimum 2-phase: next tile's HBM latency hides under MFMA);
// (b) XCD-bijective block remap + nt-major in-group order for per-XCD-L2 panel reuse.
// FFN1: 128x128, K=1024;   H = relu(xb[perm] @ w1t^T + b1), bf16 out
// FFN2: 128x128, K=4096 split-K x2; out[perm] += H @ w2t^T (+ b2 on split 0), fp32 atomics
#define STAGE(BUF, KK) do { \
    _Pragma("unroll") \
    for (int i_ = 0; i_ < 4; ++i_) { \
        GLDS(arow[i_] + (KK), &As[BUF][(i_ * 256 + tid) * 8]); \
        GLDS(brow[i_] + (KK), &Bs[BUF][(i_ * 256 + tid) * 8]); \
    } } while (0)

#define COMPUTE(BUF) do { \
    _Pragma("unroll") \
    for (int ks_ = 0; ks_ < 2; ++ks_) { \
        short8 af[4], bfr[4]; \
        _Pragma("unroll") \
        for (int m_ = 0; m_ < 4; ++m_) { \
            int R_ = wm + m_ * 16 + (lane & 15); \
            int s_ = (ks_ * 4 + (lane >> 4)) ^ (R_ & 7); \
            af[m_] = *(const short8*)&As[BUF][R_ * 64 + s_ * 8]; \
        } \
        _Pragma("unroll") \
        for (int n_ = 0; n_ < 4; ++n_) { \
            int R_ = wn + n_ * 16 + (lane & 15); \
            int s_ = (ks_ * 4 + (lane >> 4)) ^ (R_ & 7); \
            bfr[n_] = *(const short8*)&Bs[BUF][R_ * 64 + s_ * 8]; \
        } \
        _Pragma("unroll") \
        for (int m_ = 0; m_ < 4; ++m_) \
            _Pragma("unroll") \
            for (int n_ = 0; n_ < 4; ++n_) \
                acc[m_][n_] = __builtin_amdgcn_mfma_f32_16x16x32_bf16(af[m_], bfr[n_], acc[m_][n_], 0, 0, 0); \
    } } while (0)

template<bool FFN1>
__global__ __launch_bounds__(256) void ffn_gemm(
    const unsigned short* __restrict__ A,
    const unsigned short* __restrict__ Bt,
    const float* __restrict__ bias,
    const int* __restrict__ ctrl,
    const int* __restrict__ perm,
    unsigned short* __restrict__ Hout,
    float* __restrict__ Yout) {
    constexpr int K  = FFN1 ? DM : DF;
    constexpr int N  = FFN1 ? DF : DM;
    constexpr int KS = FFN1 ? 1 : 2;        // split-K factor
    constexpr int KLEN = K / KS;
    constexpr int NT = N / 128;             // 32 / 8
    constexpr int G = 8;                    // m-tiles per swizzle group
    constexpr int INNER = NT * KS;          // blocks per m-tile
    constexpr int NKI = KLEN / 64;          // K-steps (16 / 32), even

    // XCD-bijective remap (m204): XCD k owns a contiguous chunk of logical block ids,
    // so panel-sharing neighbors hit the same per-XCD L2.
    int nwg = gridDim.x;
    int bo = blockIdx.x;
    int q = nwg >> 3, r = nwg & 7;
    int xcd = bo & 7, lid = bo >> 3;
    int b = (xcd < r ? xcd * (q + 1) : r * (q + 1) + (xcd - r) * q) + lid;

    int grp = b / (G * INNER);
    int ii = b % (G * INNER);
    // nt-major within group: 8*KS consecutive logical blocks share one B-panel,
    // group's 8 A-tiles stay L2-resident across the nt sweep.
    int nt  = ii / (G * KS);
    int rem = ii % (G * KS);
    int til = grp * G + rem / KS;
    int ksp = rem % KS;
    if (til >= ctrl[25]) return;
    int e       = ctrl[32 + 3 * til];
    int rowbase = ctrl[33 + 3 * til];
    int rows    = ctrl[34 + 3 * til];

    __shared__ __align__(16) unsigned short As[2][128 * 64];
    __shared__ __align__(16) unsigned short Bs[2][128 * 64];

    int tid = threadIdx.x;
    int lane = tid & 63;
    int wave = tid >> 6;
    int wm = (wave & 1) * 64;
    int wn = (wave >> 1) * 64;

    // staging source pointers: LDS chunk c = r*8 + slot; global chunk gk = slot ^ (r&7)
    const unsigned short* arow[4];
    const unsigned short* brow[4];
    const unsigned short* bbase = Bt + (size_t)e * N * K + (size_t)(nt * 128) * K;
#pragma unroll
    for (int i = 0; i < 4; ++i) {
        int c = i * 256 + tid;
        int rr2 = c >> 3;
        int gk = (c & 7) ^ (rr2 & 7);
        int rr = rr2 < rows ? rr2 : rows - 1;   // clamp partial tile
        int cr = rowbase + rr;
        int srow = FFN1 ? perm[cr] : cr;
        arow[i] = A + (size_t)srow * K + gk * 8;
        brow[i] = bbase + (size_t)rr2 * K + gk * 8;
    }

    floatx4 acc[4][4];
#pragma unroll
    for (int i = 0; i < 4; ++i)
#pragma unroll
        for (int j = 0; j < 4; ++j) acc[i][j] = floatx4{0.f, 0.f, 0.f, 0.f};

    int kk0 = ksp * KLEN;

    // ---- 2-phase double-buffered pipeline: 1 barrier per K-step ----
    STAGE(0, kk0);
    __syncthreads();                        // buf0 landed (sync drains vmcnt)
#pragma unroll 1
    for (int t = 0; t < NKI; t += 2) {
        int kk = kk0 + t * 64;
        STAGE(1, kk + 64);                  // prefetch next under compute
        COMPUTE(0);
        __syncthreads();                    // buf1 landed; all waves done reading buf0
        if (t + 2 < NKI) STAGE(0, kk + 128);
        COMPUTE(1);
        __syncthreads();                    // buf0 landed; all waves done reading buf1
    }

    // epilogue; C/D layout: col = lane&15, row = (lane>>4)*4 + reg
    int col0 = nt * 128 + wn + (lane & 15);
    int rowq = (lane >> 4) * 4;
    float bv[4];
#pragma unroll
    for (int n = 0; n < 4; ++n) bv[n] = (FFN1 || ksp == 0) ? bias[e * N + col0 + n * 16] : 0.f;

#pragma unroll
    for (int m = 0; m < 4; ++m) {
#pragma unroll
        for (int r2 = 0; r2 < 4; ++r2) {
            int lr = wm + m * 16 + rowq + r2;
            if (lr < rows) {
                if (FFN1) {
                    unsigned short* hr = Hout + (size_t)(rowbase + lr) * DF + col0;
#pragma unroll
                    for (int n = 0; n < 4; ++n) {
                        float v = acc[m][n][r2] + bv[n];
                        v = v > 0.f ? v : 0.f;
                        hr[n * 16] = f2bf(v);
                    }
                } else {
                    float* yr = Yout + (size_t)perm[rowbase + lr] * DM + col0;
#pragma unroll
                    for (int n = 0; n < 4; ++n)
                        atomicAdd(&yr[n * 16], acc[m][n][r2] + bv[n]);
                }
            }
        }
    }
}

#undef STAGE
#undef COMPUTE

extern "C" void kernel_launch(void* const* d_in, const int* in_sizes, int n_in,
                              void* d_out, int out_size, void* d_ws, size_t ws_size,
                              hipStream_t stream) {
    const float* x  = (const float*)d_in[0];
    const float* w1 = (const float*)d_in[1];
    const float* b1 = (const float*)d_in[2];
    const float* w2 = (const float*)d_in[3];
    const float* b2 = (const float*)d_in[4];
    const float* gw = (const float*)d_in[5];
    const float* gb = (const float*)d_in[6];
    float* out = (float*)d_out;

    // workspace carve-up
    char* ws = (char*)d_ws;
    int* ctrl = (int*)ws;                                   // 1 KiB control block
    int* top1 = (int*)(ws + 1024);                          // 8192 ints
    int* perm = (int*)(ws + 1024 + 32768);                  // 8192 ints
    size_t o = 66560;                                       // 256B-aligned
    unsigned short* xb  = (unsigned short*)(ws + o);        o += (size_t)NTOK * DM * 2;      // 16.8 MB
    unsigned short* w1t = (unsigned short*)(ws + o);        o += (size_t)NE * DM * DF * 2;   // 67 MB
    unsigned short* w2t = (unsigned short*)(ws + o);        o += (size_t)NE * DM * DF * 2;   // 67 MB
    unsigned short* H   = (unsigned short*)(ws + o);        // 67 MB  (total ~218 MB)

    hipMemsetAsync(ctrl, 0, 1024, stream);
    hipMemsetAsync(out, 0, (size_t)out_size * 4, stream);   // required: FFN2 accumulates atomically
    gate_kernel<<<NTOK, 64, 0, stream>>>(x, gw, gb, top1, xb);
    count_kernel<<<NTOK / 256, 256, 0, stream>>>(top1, ctrl);
    prefix_kernel<<<1, 64, 0, stream>>>(ctrl);
    scatter_kernel<<<NTOK / 256, 256, 0, stream>>>(top1, ctrl, perm);
    transpose_bf16<<<NE * (DM / 64) * (DF / 64), 256, 0, stream>>>(w1, w1t, DM, DF);
    transpose_bf16<<<NE * (DF / 64) * (DM / 64), 256, 0, stream>>>(w2, w2t, DF, DM);
    ffn_gemm<true ><<<MT_LAUNCH * (DF / 128), 256, 0, stream>>>(xb, w1t, b1, ctrl, perm, H, nullptr);
    ffn_gemm<false><<<MT_LAUNCH * (DM / 128) * 2, 256, 0, stream>>>(H, w2t, b2, ctrl, perm, nullptr, out);
}

// Round 3
// 625.840 us; speedup vs baseline: 1.0876x; 1.0313x over previous
//
#include <hip/hip_runtime.h>
#include <stdint.h>

#define DM 1024
#define DF 4096
#define NE 8
#define NTOK 8192   // B*S = 4*2048
#define MT128 72    // >= max 128-row tiles (71), /8
#define MT256 40    // >= max 256-row tiles (39), /8

typedef __attribute__((ext_vector_type(8))) short short8;
typedef __attribute__((ext_vector_type(8))) unsigned short ushort8v;
typedef __attribute__((ext_vector_type(4))) float floatx4;

__device__ inline unsigned short f2bf(float f) {
    union { float f; unsigned u; } v; v.f = f;
    unsigned u = v.u;
    u += 0x7fffu + ((u >> 16) & 1u);   // round-to-nearest-even
    return (unsigned short)(u >> 16);
}

#define GLDS(g, l) __builtin_amdgcn_global_load_lds( \
    (const __attribute__((address_space(1))) void*)(g), \
    (__attribute__((address_space(3))) void*)(l), 16, 0, 0)

#define VMW(N)  asm volatile("s_waitcnt vmcnt(" #N ")" ::: "memory")
#define LGKM0   asm volatile("s_waitcnt lgkmcnt(0)" ::: "memory")
#define SCHED0  __builtin_amdgcn_sched_barrier(0)
#define BAR     __builtin_amdgcn_s_barrier()

// ---------------- gating: one wave per token, fp64 accumulation; fused x->bf16 ----------------
__global__ void gate_kernel(const float* __restrict__ x, const float* __restrict__ gw,
                            const float* __restrict__ gb, int* __restrict__ top1,
                            unsigned short* __restrict__ xb) {
    int t = blockIdx.x;
    int lane = threadIdx.x;            // 64 threads
    const float* xr = x + (size_t)t * DM;
    unsigned short* xbr = xb + (size_t)t * DM;
    double acc[NE];
#pragma unroll
    for (int e = 0; e < NE; ++e) acc[e] = 0.0;
    for (int j = 0; j < DM / 64; ++j) {
        int d = j * 64 + lane;
        float xf = xr[d];
        xbr[d] = f2bf(xf);
        double xv = (double)xf;
        const float* g = gw + (size_t)d * NE;
#pragma unroll
        for (int e = 0; e < NE; ++e) acc[e] = fma(xv, (double)g[e], acc[e]);
    }
#pragma unroll
    for (int e = 0; e < NE; ++e) {
        for (int off = 32; off > 0; off >>= 1)
            acc[e] += __shfl_down(acc[e], off, 64);
    }
    if (lane == 0) {
        int best = 0;
        double bv = acc[0] + (double)gb[0];
        for (int e = 1; e < NE; ++e) {
            double v = acc[e] + (double)gb[e];
            if (v > bv) { bv = v; best = e; }   // strict > == first-max (jnp.argmax)
        }
        top1[t] = best;
    }
}

// ctrl ints: [0..7] counts, [8..16] offsets (+total), [17..24] cursors,
// [25] ntiles256, [26] ntiles128,
// [32+3i..] 256-tile table (expert, rowbase, rows)  -- max 39 tiles
// [160+3i..] 128-tile table                         -- max 71 tiles
__global__ void count_kernel(const int* __restrict__ top1, int* __restrict__ ctrl) {
    int t = blockIdx.x * 256 + threadIdx.x;
    int e = top1[t];
    int lane = threadIdx.x & 63;
#pragma unroll
    for (int ex = 0; ex < NE; ++ex) {
        unsigned long long m = __ballot(e == ex);
        if (m != 0ull && lane == (__ffsll((long long)m) - 1))
            atomicAdd(&ctrl[ex], __popcll(m));
    }
}

__global__ void prefix_kernel(int* ctrl) {
    if (threadIdx.x == 0) {
        int s = 0, t256 = 0, t128 = 0;
        for (int e = 0; e < NE; ++e) {
            int cnt = ctrl[e];
            ctrl[8 + e] = s; ctrl[17 + e] = s;
            for (int m = 0; m * 256 < cnt; ++m) {
                ctrl[32 + 3 * t256] = e;
                ctrl[33 + 3 * t256] = s + m * 256;
                int rr = cnt - m * 256;
                ctrl[34 + 3 * t256] = rr < 256 ? rr : 256;
                ++t256;
            }
            for (int m = 0; m * 128 < cnt; ++m) {
                ctrl[160 + 3 * t128] = e;
                ctrl[161 + 3 * t128] = s + m * 128;
                int rr = cnt - m * 128;
                ctrl[162 + 3 * t128] = rr < 128 ? rr : 128;
                ++t128;
            }
            s += cnt;
        }
        ctrl[16] = s;
        ctrl[25] = t256;
        ctrl[26] = t128;
    }
}

__global__ void scatter_kernel(const int* __restrict__ top1, int* __restrict__ ctrl,
                               int* __restrict__ perm) {
    int t = blockIdx.x * 256 + threadIdx.x;
    int e = top1[t];
    int lane = threadIdx.x & 63;
#pragma unroll
    for (int ex = 0; ex < NE; ++ex) {
        unsigned long long m = __ballot(e == ex);
        if (m == 0ull) continue;
        int leader = __ffsll((long long)m) - 1;
        int base = 0;
        if (lane == leader) base = atomicAdd(&ctrl[17 + ex], __popcll(m));
        base = __shfl(base, leader, 64);
        if (e == ex) {
            int pos = __popcll(m & ((1ull << lane) - 1ull));
            perm[base + pos] = t;   // compacted position -> token id
        }
    }
}

// -------- tiled transpose + convert: src [E][R][C] f32 -> dst [E][C][R] bf16 --------
__global__ void transpose_bf16(const float* __restrict__ src, unsigned short* __restrict__ dst,
                               int R, int C) {
    __shared__ float tile[64][65];
    int tilesR = R >> 6, tilesC = C >> 6;
    int bid = blockIdx.x;
    int e = bid / (tilesR * tilesC);
    int rem = bid % (tilesR * tilesC);
    int tr = rem / tilesC, tc = rem % tilesC;
    const float* s = src + (size_t)e * R * C + (size_t)(tr * 64) * C + tc * 64;
    unsigned short* d = dst + (size_t)e * R * C + (size_t)(tc * 64) * R + tr * 64;
    int tid = threadIdx.x;
#pragma unroll
    for (int i = 0; i < 4; ++i) {
        int idx = i * 256 + tid;          // 0..1023
        int r = idx >> 4, c4 = (idx & 15) * 4;
        float4 v = *(const float4*)(s + (size_t)r * C + c4);
        tile[r][c4 + 0] = v.x; tile[r][c4 + 1] = v.y;
        tile[r][c4 + 2] = v.z; tile[r][c4 + 3] = v.w;
    }
    __syncthreads();
#pragma unroll
    for (int i = 0; i < 2; ++i) {
        int idx = i * 256 + tid;          // 0..511
        int c = idx >> 3, r8 = (idx & 7) * 8;
        ushort8v o;
#pragma unroll
        for (int j = 0; j < 8; ++j) o[j] = f2bf(tile[r8 + j][c]);
        *(ushort8v*)(d + (size_t)c * R + r8) = o;
    }
}

// ================= FFN1: 256x256 tile, 8 waves, ring-4 BK=32 slabs, counted vmcnt =================
// LDS slab: [256 rows][4 slots][8 bf16]; slot s' holds global k-chunk s'^((row>>1)&3)
// (pre-swizzled GLOBAL source, linear GLDS dest). Fragment ds_read_b128 -> 2-way banks (free).
// Schedule (T3+T4+T5): stage runs 3 slabs ahead; ONE s_barrier per slab (32 MFMA/barrier);
// per-wave vmcnt(8) before the slab-end barrier => slab s+1 fully landed for all waves after it.
// Ring overwrite safety: slab s+3 -> buf[(s-1)&3], whose readers drained lgkmcnt(0) before
// slab s-1's end barrier. Slab loop unrolled x4 + peeled tail so ALL ring indices are
// compile-time (direct __shared__ access -> guaranteed ds_read, vmcnt ledger only counts GLDS).
// Tail peel: vmcnt 8 / 4 / 0 literals on slabs 29/30/31's predecessors.
#define F1_SLAB(u, SU, STG, W) do { \
    if (STG) { \
        int kk_ = ((SU) + 3) * 32; \
        GLDS(ap0 + kk_, &As[((u) + 3) & 3][(size_t)tid * 8]); \
        GLDS(ap1 + kk_, &As[((u) + 3) & 3][(size_t)(512 + tid) * 8]); \
        GLDS(bp0 + kk_, &Bs[((u) + 3) & 3][(size_t)tid * 8]); \
        GLDS(bp1 + kk_, &Bs[((u) + 3) & 3][(size_t)(512 + tid) * 8]); \
    } \
    short8 af[8], bf[4]; \
    _Pragma("unroll") \
    for (int m_ = 0; m_ < 8; ++m_) af[m_] = *(const short8*)&As[u][aoff[m_]]; \
    _Pragma("unroll") \
    for (int n_ = 0; n_ < 4; ++n_) bf[n_] = *(const short8*)&Bs[u][boff[n_]]; \
    LGKM0; SCHED0; \
    __builtin_amdgcn_s_setprio(1); \
    _Pragma("unroll") \
    for (int m_ = 0; m_ < 8; ++m_) \
        _Pragma("unroll") \
        for (int n_ = 0; n_ < 4; ++n_) \
            acc[m_][n_] = __builtin_amdgcn_mfma_f32_16x16x32_bf16(af[m_], bf[n_], acc[m_][n_], 0, 0, 0); \
    __builtin_amdgcn_s_setprio(0); \
    W; SCHED0; BAR; \
} while (0)

__global__ __launch_bounds__(512, 2) void ffn1_gemm(
    const unsigned short* __restrict__ A,    // xb [NTOK][DM]
    const unsigned short* __restrict__ Bt,   // w1t [E][DF][DM]
    const float* __restrict__ bias,          // b1 [E][DF]
    const int* __restrict__ ctrl,
    const int* __restrict__ perm,
    unsigned short* __restrict__ Hout) {     // H [NTOK][DF] compacted rows
    constexpr int K = DM;          // 1024
    constexpr int N = DF;          // 4096
    constexpr int NT = N / 256;    // 16
    constexpr int NKI = K / 32;    // 32 slabs
    constexpr int SLABSZ = 256 * 32; // ushorts (16 KiB)
    constexpr int G = 8;

    // XCD-bijective remap + nt-major group order
    int nwg = gridDim.x;
    int bo = blockIdx.x;
    int q = nwg >> 3, r = nwg & 7;
    int xcd = bo & 7, lid = bo >> 3;
    int b = (xcd < r ? xcd * (q + 1) : r * (q + 1) + (xcd - r) * q) + lid;

    int grp = b / (G * NT);
    int ii = b % (G * NT);
    int nt = ii / G;
    int til = grp * G + (ii % G);
    if (til >= ctrl[25]) return;
    int e       = ctrl[32 + 3 * til];
    int rowbase = ctrl[33 + 3 * til];
    int rows    = ctrl[34 + 3 * til];

    __shared__ __align__(16) unsigned short As[4][SLABSZ];
    __shared__ __align__(16) unsigned short Bs[4][SLABSZ];

    int tid = threadIdx.x, lane = tid & 63, wave = tid >> 6;
    int wm = (wave >> 2) * 128;   // 0 / 128
    int wn = (wave & 3) * 64;     // 0..192

    // staging: each thread stages 2 rows/slab per operand: row tid>>2 and 128+(tid>>2)
    int rA0 = tid >> 2, rA1 = 128 + (tid >> 2);
    int kofs = ((tid & 3) ^ ((tid >> 3) & 3)) * 8;   // pre-swizzled global k-chunk
    int c0 = rowbase + (rA0 < rows ? rA0 : rows - 1);
    int c1 = rowbase + (rA1 < rows ? rA1 : rows - 1);
    const unsigned short* ap0 = A + (size_t)perm[c0] * K + kofs;
    const unsigned short* ap1 = A + (size_t)perm[c1] * K + kofs;
    const unsigned short* bb  = Bt + (size_t)e * N * K + (size_t)(nt * 256) * K + kofs;
    const unsigned short* bp0 = bb + (size_t)rA0 * K;
    const unsigned short* bp1 = bb + (size_t)rA1 * K;

    // fragment LDS offsets (ushort units), constant per lane; chunk g=lane>>4 at slot g^((R>>1)&3)
    int aoff[8], boff[4];
#pragma unroll
    for (int m = 0; m < 8; ++m) {
        int R = wm + m * 16 + (lane & 15);
        aoff[m] = R * 32 + (((lane >> 4) ^ ((R >> 1) & 3)) * 8);
    }
#pragma unroll
    for (int n = 0; n < 4; ++n) {
        int R = wn + n * 16 + (lane & 15);
        boff[n] = R * 32 + (((lane >> 4) ^ ((R >> 1) & 3)) * 8);
    }

    floatx4 acc[8][4];
#pragma unroll
    for (int i = 0; i < 8; ++i)
#pragma unroll
        for (int j = 0; j < 4; ++j) acc[i][j] = floatx4{0.f, 0.f, 0.f, 0.f};

    // prologue: stage slabs 0,1,2 (12 GLDS in flight); vmcnt(8) -> slab 0 landed
#pragma unroll
    for (int s = 0; s < 3; ++s) {
        GLDS(ap0 + s * 32, &As[s][(size_t)tid * 8]);
        GLDS(ap1 + s * 32, &As[s][(size_t)(512 + tid) * 8]);
        GLDS(bp0 + s * 32, &Bs[s][(size_t)tid * 8]);
        GLDS(bp1 + s * 32, &Bs[s][(size_t)(512 + tid) * 8]);
    }
    VMW(8); SCHED0; BAR;

#pragma unroll 1
    for (int s = 0; s < NKI - 4; s += 4) {   // slabs 0..27, each stages slab su+3 (3..30)
        F1_SLAB(0, s + 0, 1, VMW(8));
        F1_SLAB(1, s + 1, 1, VMW(8));
        F1_SLAB(2, s + 2, 1, VMW(8));
        F1_SLAB(3, s + 3, 1, VMW(8));
    }
    // tail: slabs 28..31 (28 stages slab 31; then drain 8 -> 4 -> 0)
    F1_SLAB(0, NKI - 4, 1, VMW(8));
    F1_SLAB(1, NKI - 3, 0, VMW(4));
    F1_SLAB(2, NKI - 2, 0, VMW(0));
    F1_SLAB(3, NKI - 1, 0, (void)0);

    // epilogue; C/D layout: col = lane&15, row = (lane>>4)*4 + reg
    int col0 = nt * 256 + wn + (lane & 15);
    int rowq = (lane >> 4) * 4;
    float bv[4];
#pragma unroll
    for (int n = 0; n < 4; ++n) bv[n] = bias[e * N + col0 + n * 16];

#pragma unroll
    for (int m = 0; m < 8; ++m) {
#pragma unroll
        for (int r2 = 0; r2 < 4; ++r2) {
            int lr = wm + m * 16 + rowq + r2;
            if (lr < rows) {
                unsigned short* hr = Hout + (size_t)(rowbase + lr) * DF + col0;
#pragma unroll
                for (int n = 0; n < 4; ++n) {
                    float v = acc[m][n][r2] + bv[n];
                    v = v > 0.f ? v : 0.f;
                    hr[n * 16] = f2bf(v);
                }
            }
        }
    }
}
#undef F1_SLAB

// ================= FFN2: 128x128, 2-phase dbuf (verified structure), full K, no atomics =========
// out[perm] = H @ w2t^T + b2 ; every output element written exactly once -> plain stores,
// no split-K, no memset. Uses the 128-row tile table at ctrl[160..], count ctrl[26].
__global__ __launch_bounds__(256) void ffn2_gemm(
    const unsigned short* __restrict__ A,    // H [NTOK][DF] compacted
    const unsigned short* __restrict__ Bt,   // w2t [E][DM][DF]
    const float* __restrict__ bias,          // b2 [E][DM]
    const int* __restrict__ ctrl,
    const int* __restrict__ perm,
    float* __restrict__ Yout) {
    constexpr int K = DF;          // 4096
    constexpr int N = DM;          // 1024
    constexpr int NT = N / 128;    // 8
    constexpr int G = 8;
    constexpr int NKI = K / 64;    // 64 K-steps

    int nwg = gridDim.x;
    int bo = blockIdx.x;
    int q = nwg >> 3, r = nwg & 7;
    int xcd = bo & 7, lid = bo >> 3;
    int b = (xcd < r ? xcd * (q + 1) : r * (q + 1) + (xcd - r) * q) + lid;

    int grp = b / (G * NT);
    int ii = b % (G * NT);
    int nt = ii / G;
    int til = grp * G + (ii % G);
    if (til >= ctrl[26]) return;
    int e       = ctrl[160 + 3 * til];
    int rowbase = ctrl[161 + 3 * til];
    int rows    = ctrl[162 + 3 * til];

    __shared__ __align__(16) unsigned short As[2][128 * 64];
    __shared__ __align__(16) unsigned short Bs[2][128 * 64];

    int tid = threadIdx.x;
    int lane = tid & 63;
    int wave = tid >> 6;
    int wm = (wave & 1) * 64;
    int wn = (wave >> 1) * 64;

    const unsigned short* arow[4];
    const unsigned short* brow[4];
    const unsigned short* bbase = Bt + (size_t)e * N * K + (size_t)(nt * 128) * K;
#pragma unroll
    for (int i = 0; i < 4; ++i) {
        int c = i * 256 + tid;
        int rr2 = c >> 3;
        int gk = (c & 7) ^ (rr2 & 7);
        int rr = rr2 < rows ? rr2 : rows - 1;
        arow[i] = A + (size_t)(rowbase + rr) * K + gk * 8;
        brow[i] = bbase + (size_t)rr2 * K + gk * 8;
    }

    floatx4 acc[4][4];
#pragma unroll
    for (int i = 0; i < 4; ++i)
#pragma unroll
        for (int j = 0; j < 4; ++j) acc[i][j] = floatx4{0.f, 0.f, 0.f, 0.f};

#define F2_STAGE(BUF, KK) do { \
    _Pragma("unroll") \
    for (int i_ = 0; i_ < 4; ++i_) { \
        GLDS(arow[i_] + (KK), &As[BUF][(i_ * 256 + tid) * 8]); \
        GLDS(brow[i_] + (KK), &Bs[BUF][(i_ * 256 + tid) * 8]); \
    } } while (0)

#define F2_COMPUTE(BUF) do { \
    _Pragma("unroll") \
    for (int ks_ = 0; ks_ < 2; ++ks_) { \
        short8 af[4], bfr[4]; \
        _Pragma("unroll") \
        for (int m_ = 0; m_ < 4; ++m_) { \
            int R_ = wm + m_ * 16 + (lane & 15); \
            int s_ = (ks_ * 4 + (lane >> 4)) ^ (R_ & 7); \
            af[m_] = *(const short8*)&As[BUF][R_ * 64 + s_ * 8]; \
        } \
        _Pragma("unroll") \
        for (int n_ = 0; n_ < 4; ++n_) { \
            int R_ = wn + n_ * 16 + (lane & 15); \
            int s_ = (ks_ * 4 + (lane >> 4)) ^ (R_ & 7); \
            bfr[n_] = *(const short8*)&Bs[BUF][R_ * 64 + s_ * 8]; \
        } \
        _Pragma("unroll") \
        for (int m_ = 0; m_ < 4; ++m_) \
            _Pragma("unroll") \
            for (int n_ = 0; n_ < 4; ++n_) \
                acc[m_][n_] = __builtin_amdgcn_mfma_f32_16x16x32_bf16(af[m_], bfr[n_], acc[m_][n_], 0, 0, 0); \
    } } while (0)

    F2_STAGE(0, 0);
    __syncthreads();
#pragma unroll 1
    for (int t = 0; t < NKI; t += 2) {
        int kk = t * 64;
        F2_STAGE(1, kk + 64);
        F2_COMPUTE(0);
        __syncthreads();
        if (t + 2 < NKI) F2_STAGE(0, kk + 128);
        F2_COMPUTE(1);
        __syncthreads();
    }
#undef F2_STAGE
#undef F2_COMPUTE

    int col0 = nt * 128 + wn + (lane & 15);
    int rowq = (lane >> 4) * 4;
    float bv[4];
#pragma unroll
    for (int n = 0; n < 4; ++n) bv[n] = bias[e * N + col0 + n * 16];

#pragma unroll
    for (int m = 0; m < 4; ++m) {
#pragma unroll
        for (int r2 = 0; r2 < 4; ++r2) {
            int lr = wm + m * 16 + rowq + r2;
            if (lr < rows) {
                float* yr = Yout + (size_t)perm[rowbase + lr] * DM + col0;
#pragma unroll
                for (int n = 0; n < 4; ++n)
                    yr[n * 16] = acc[m][n][r2] + bv[n];
            }
        }
    }
}

extern "C" void kernel_launch(void* const* d_in, const int* in_sizes, int n_in,
                              void* d_out, int out_size, void* d_ws, size_t ws_size,
                              hipStream_t stream) {
    const float* x  = (const float*)d_in[0];
    const float* w1 = (const float*)d_in[1];
    const float* b1 = (const float*)d_in[2];
    const float* w2 = (const float*)d_in[3];
    const float* b2 = (const float*)d_in[4];
    const float* gw = (const float*)d_in[5];
    const float* gb = (const float*)d_in[6];
    float* out = (float*)d_out;

    // workspace carve-up
    char* ws = (char*)d_ws;
    int* ctrl = (int*)ws;                                   // 2 KiB control block
    int* top1 = (int*)(ws + 2048);                          // 8192 ints
    int* perm = (int*)(ws + 2048 + 32768);                  // 8192 ints
    size_t o = 67584;                                       // 256B-aligned
    unsigned short* xb  = (unsigned short*)(ws + o);        o += (size_t)NTOK * DM * 2;      // 16.8 MB
    unsigned short* w1t = (unsigned short*)(ws + o);        o += (size_t)NE * DM * DF * 2;   // 67 MB
    unsigned short* w2t = (unsigned short*)(ws + o);        o += (size_t)NE * DM * DF * 2;   // 67 MB
    unsigned short* H   = (unsigned short*)(ws + o);        // 67 MB  (total ~218 MB)

    hipMemsetAsync(ctrl, 0, 2048, stream);
    gate_kernel<<<NTOK, 64, 0, stream>>>(x, gw, gb, top1, xb);
    count_kernel<<<NTOK / 256, 256, 0, stream>>>(top1, ctrl);
    prefix_kernel<<<1, 64, 0, stream>>>(ctrl);
    scatter_kernel<<<NTOK / 256, 256, 0, stream>>>(top1, ctrl, perm);
    transpose_bf16<<<NE * (DM / 64) * (DF / 64), 256, 0, stream>>>(w1, w1t, DM, DF);
    transpose_bf16<<<NE * (DF / 64) * (DM / 64), 256, 0, stream>>>(w2, w2t, DF, DM);
    ffn1_gemm<<<MT256 * (DF / 256), 512, 0, stream>>>(xb, w1t, b1, ctrl, perm, H);
    ffn2_gemm<<<MT128 * (DM / 128), 256, 0, stream>>>(H, w2t, b2, ctrl, perm, out);
}

// Round 4
// 585.816 us; speedup vs baseline: 1.1619x; 1.0683x over previous
//
#include <hip/hip_runtime.h>
#include <stdint.h>

#define DM 1024
#define DF 4096
#define NE 8
#define NTOK 8192   // B*S = 4*2048
#define MT256 40    // >= max 256-row tiles (39), /8

typedef __attribute__((ext_vector_type(8))) short short8;
typedef __attribute__((ext_vector_type(8))) unsigned short ushort8v;
typedef __attribute__((ext_vector_type(4))) float floatx4;

__device__ inline unsigned short f2bf(float f) {
    union { float f; unsigned u; } v; v.f = f;
    unsigned u = v.u;
    u += 0x7fffu + ((u >> 16) & 1u);   // round-to-nearest-even
    return (unsigned short)(u >> 16);
}

#define GLDS(g, l) __builtin_amdgcn_global_load_lds( \
    (const __attribute__((address_space(1))) void*)(g), \
    (__attribute__((address_space(3))) void*)(l), 16, 0, 0)

#define VMW(N)  asm volatile("s_waitcnt vmcnt(" #N ")" ::: "memory")
#define LGKM0   asm volatile("s_waitcnt lgkmcnt(0)" ::: "memory")
#define SCHED0  __builtin_amdgcn_sched_barrier(0)
#define BAR     __builtin_amdgcn_s_barrier()

// ---------------- gating: one wave per token, fp64 accumulation; fused x->bf16 ----------------
__global__ void gate_kernel(const float* __restrict__ x, const float* __restrict__ gw,
                            const float* __restrict__ gb, int* __restrict__ top1,
                            unsigned short* __restrict__ xb) {
    int t = blockIdx.x;
    int lane = threadIdx.x;            // 64 threads
    const float* xr = x + (size_t)t * DM;
    unsigned short* xbr = xb + (size_t)t * DM;
    double acc[NE];
#pragma unroll
    for (int e = 0; e < NE; ++e) acc[e] = 0.0;
    for (int j = 0; j < DM / 64; ++j) {
        int d = j * 64 + lane;
        float xf = xr[d];
        xbr[d] = f2bf(xf);
        double xv = (double)xf;
        const float* g = gw + (size_t)d * NE;
#pragma unroll
        for (int e = 0; e < NE; ++e) acc[e] = fma(xv, (double)g[e], acc[e]);
    }
#pragma unroll
    for (int e = 0; e < NE; ++e) {
        for (int off = 32; off > 0; off >>= 1)
            acc[e] += __shfl_down(acc[e], off, 64);
    }
    if (lane == 0) {
        int best = 0;
        double bv = acc[0] + (double)gb[0];
        for (int e = 1; e < NE; ++e) {
            double v = acc[e] + (double)gb[e];
            if (v > bv) { bv = v; best = e; }   // strict > == first-max (jnp.argmax)
        }
        top1[t] = best;
    }
}

// ctrl ints: [0..7] counts, [8..16] offsets (+total), [17..24] cursors, [25] ntiles256,
// [32+3i..] 256-tile table (expert, rowbase, rows)  -- max 39 tiles
__global__ void count_kernel(const int* __restrict__ top1, int* __restrict__ ctrl) {
    int t = blockIdx.x * 256 + threadIdx.x;
    int e = top1[t];
    int lane = threadIdx.x & 63;
#pragma unroll
    for (int ex = 0; ex < NE; ++ex) {
        unsigned long long m = __ballot(e == ex);
        if (m != 0ull && lane == (__ffsll((long long)m) - 1))
            atomicAdd(&ctrl[ex], __popcll(m));
    }
}

__global__ void prefix_kernel(int* ctrl) {
    if (threadIdx.x == 0) {
        int s = 0, t256 = 0;
        for (int e = 0; e < NE; ++e) {
            int cnt = ctrl[e];
            ctrl[8 + e] = s; ctrl[17 + e] = s;
            for (int m = 0; m * 256 < cnt; ++m) {
                ctrl[32 + 3 * t256] = e;
                ctrl[33 + 3 * t256] = s + m * 256;
                int rr = cnt - m * 256;
                ctrl[34 + 3 * t256] = rr < 256 ? rr : 256;
                ++t256;
            }
            s += cnt;
        }
        ctrl[16] = s;
        ctrl[25] = t256;
    }
}

__global__ void scatter_kernel(const int* __restrict__ top1, int* __restrict__ ctrl,
                               int* __restrict__ perm) {
    int t = blockIdx.x * 256 + threadIdx.x;
    int e = top1[t];
    int lane = threadIdx.x & 63;
#pragma unroll
    for (int ex = 0; ex < NE; ++ex) {
        unsigned long long m = __ballot(e == ex);
        if (m == 0ull) continue;
        int leader = __ffsll((long long)m) - 1;
        int base = 0;
        if (lane == leader) base = atomicAdd(&ctrl[17 + ex], __popcll(m));
        base = __shfl(base, leader, 64);
        if (e == ex) {
            int pos = __popcll(m & ((1ull << lane) - 1ull));
            perm[base + pos] = t;   // compacted position -> token id
        }
    }
}

// -------- fused tiled transpose + convert for BOTH weights: [E][R][C] f32 -> [E][C][R] bf16 ----
__global__ void transpose_both(const float* __restrict__ w1, unsigned short* __restrict__ w1t,
                               const float* __restrict__ w2, unsigned short* __restrict__ w2t) {
    constexpr int NT1 = NE * (DM / 64) * (DF / 64);   // 8192
    __shared__ float tile[64][65];
    int bid = blockIdx.x;
    const float* src; unsigned short* dst; int R, C;
    if (bid < NT1) { src = w1; dst = w1t; R = DM; C = DF; }
    else           { bid -= NT1; src = w2; dst = w2t; R = DF; C = DM; }
    int tilesR = R >> 6, tilesC = C >> 6;
    int e = bid / (tilesR * tilesC);
    int rem = bid % (tilesR * tilesC);
    int tr = rem / tilesC, tc = rem % tilesC;
    const float* s = src + (size_t)e * R * C + (size_t)(tr * 64) * C + tc * 64;
    unsigned short* d = dst + (size_t)e * R * C + (size_t)(tc * 64) * R + tr * 64;
    int tid = threadIdx.x;
#pragma unroll
    for (int i = 0; i < 4; ++i) {
        int idx = i * 256 + tid;          // 0..1023
        int r = idx >> 4, c4 = (idx & 15) * 4;
        float4 v = *(const float4*)(s + (size_t)r * C + c4);
        tile[r][c4 + 0] = v.x; tile[r][c4 + 1] = v.y;
        tile[r][c4 + 2] = v.z; tile[r][c4 + 3] = v.w;
    }
    __syncthreads();
#pragma unroll
    for (int i = 0; i < 2; ++i) {
        int idx = i * 256 + tid;          // 0..511
        int c = idx >> 3, r8 = (idx & 7) * 8;
        ushort8v o;
#pragma unroll
        for (int j = 0; j < 8; ++j) o[j] = f2bf(tile[r8 + j][c]);
        *(ushort8v*)(d + (size_t)c * R + r8) = o;
    }
}

// ================= FFN GEMM: 256x256 tile, 8 waves, ring-4 BK=32 slabs, counted vmcnt ===========
// (structure verified correct+faster as ffn1 in round 3; now templated for both FFNs)
// LDS slab: [256 rows][4 slots][8 bf16]; slot s' holds global k-chunk s'^((row>>1)&3)
// (pre-swizzled GLOBAL source, linear GLDS dest). Fragment ds_read_b128 -> 2-way banks (free).
// Schedule (T3+T4+T5): stage runs 3 slabs ahead; ONE s_barrier per slab (32 MFMA/barrier);
// per-wave vmcnt(8) before the slab-end barrier => slab s+1 fully landed for all waves after it.
// Ring overwrite safety: slab s+3 -> buf[(s-1)&3], whose readers drained lgkmcnt(0) before
// slab s-1's end barrier. Slab loop unrolled x4 + peeled tail so ALL ring indices are
// compile-time (direct __shared__ access -> guaranteed ds_read, vmcnt ledger only counts GLDS).
// Tail peel: vmcnt 8 / 4 / 0 literals.
// FFN1: H[compact] = relu(xb[perm] @ w1t^T + b1), bf16.  K=1024, 32 slabs, grid 40*16.
// FFN2: out[perm] = H[compact] @ w2t^T + b2, fp32, exactly-once stores. K=4096, 128 slabs, grid 40*4.
#define F_SLAB(u, SU, STG, W) do { \
    if (STG) { \
        int kk_ = ((SU) + 3) * 32; \
        GLDS(ap0 + kk_, &As[((u) + 3) & 3][(size_t)tid * 8]); \
        GLDS(ap1 + kk_, &As[((u) + 3) & 3][(size_t)(512 + tid) * 8]); \
        GLDS(bp0 + kk_, &Bs[((u) + 3) & 3][(size_t)tid * 8]); \
        GLDS(bp1 + kk_, &Bs[((u) + 3) & 3][(size_t)(512 + tid) * 8]); \
    } \
    short8 af[8], bf[4]; \
    _Pragma("unroll") \
    for (int m_ = 0; m_ < 8; ++m_) af[m_] = *(const short8*)&As[u][aoff[m_]]; \
    _Pragma("unroll") \
    for (int n_ = 0; n_ < 4; ++n_) bf[n_] = *(const short8*)&Bs[u][boff[n_]]; \
    LGKM0; SCHED0; \
    __builtin_amdgcn_s_setprio(1); \
    _Pragma("unroll") \
    for (int m_ = 0; m_ < 8; ++m_) \
        _Pragma("unroll") \
        for (int n_ = 0; n_ < 4; ++n_) \
            acc[m_][n_] = __builtin_amdgcn_mfma_f32_16x16x32_bf16(af[m_], bf[n_], acc[m_][n_], 0, 0, 0); \
    __builtin_amdgcn_s_setprio(0); \
    W; SCHED0; BAR; \
} while (0)

template<bool FFN1>
__global__ __launch_bounds__(512, 2) void ffn_gemm(
    const unsigned short* __restrict__ A,    // FFN1: xb [NTOK][DM]; FFN2: H [NTOK][DF] compacted
    const unsigned short* __restrict__ Bt,   // FFN1: w1t [E][DF][DM]; FFN2: w2t [E][DM][DF]
    const float* __restrict__ bias,          // b1 [E][DF] / b2 [E][DM]
    const int* __restrict__ ctrl,
    const int* __restrict__ perm,
    unsigned short* __restrict__ Hout,       // FFN1 out
    float* __restrict__ Yout) {              // FFN2 out
    constexpr int K = FFN1 ? DM : DF;        // 1024 / 4096
    constexpr int N = FFN1 ? DF : DM;        // 4096 / 1024
    constexpr int NT = N / 256;              // 16 / 4
    constexpr int NKI = K / 32;              // 32 / 128
    constexpr int SLABSZ = 256 * 32;         // ushorts (16 KiB)
    constexpr int G = 8;

    // XCD-bijective remap + nt-major group order
    int nwg = gridDim.x;
    int bo = blockIdx.x;
    int q = nwg >> 3, r = nwg & 7;
    int xcd = bo & 7, lid = bo >> 3;
    int b = (xcd < r ? xcd * (q + 1) : r * (q + 1) + (xcd - r) * q) + lid;

    int grp = b / (G * NT);
    int ii = b % (G * NT);
    int nt = ii / G;
    int til = grp * G + (ii % G);
    if (til >= ctrl[25]) return;
    int e       = ctrl[32 + 3 * til];
    int rowbase = ctrl[33 + 3 * til];
    int rows    = ctrl[34 + 3 * til];

    __shared__ __align__(16) unsigned short As[4][SLABSZ];
    __shared__ __align__(16) unsigned short Bs[4][SLABSZ];

    int tid = threadIdx.x, lane = tid & 63, wave = tid >> 6;
    int wm = (wave >> 2) * 128;   // 0 / 128
    int wn = (wave & 3) * 64;     // 0..192

    // staging: each thread stages 2 rows/slab per operand: row tid>>2 and 128+(tid>>2)
    int rA0 = tid >> 2, rA1 = 128 + (tid >> 2);
    int kofs = ((tid & 3) ^ ((tid >> 3) & 3)) * 8;   // pre-swizzled global k-chunk
    int c0 = rowbase + (rA0 < rows ? rA0 : rows - 1);
    int c1 = rowbase + (rA1 < rows ? rA1 : rows - 1);
    const unsigned short* ap0;
    const unsigned short* ap1;
    if (FFN1) {
        ap0 = A + (size_t)perm[c0] * K + kofs;
        ap1 = A + (size_t)perm[c1] * K + kofs;
    } else {
        ap0 = A + (size_t)c0 * K + kofs;
        ap1 = A + (size_t)c1 * K + kofs;
    }
    const unsigned short* bb  = Bt + (size_t)e * N * K + (size_t)(nt * 256) * K + kofs;
    const unsigned short* bp0 = bb + (size_t)rA0 * K;
    const unsigned short* bp1 = bb + (size_t)rA1 * K;

    // fragment LDS offsets (ushort units), constant per lane; chunk g=lane>>4 at slot g^((R>>1)&3)
    int aoff[8], boff[4];
#pragma unroll
    for (int m = 0; m < 8; ++m) {
        int R = wm + m * 16 + (lane & 15);
        aoff[m] = R * 32 + (((lane >> 4) ^ ((R >> 1) & 3)) * 8);
    }
#pragma unroll
    for (int n = 0; n < 4; ++n) {
        int R = wn + n * 16 + (lane & 15);
        boff[n] = R * 32 + (((lane >> 4) ^ ((R >> 1) & 3)) * 8);
    }

    floatx4 acc[8][4];
#pragma unroll
    for (int i = 0; i < 8; ++i)
#pragma unroll
        for (int j = 0; j < 4; ++j) acc[i][j] = floatx4{0.f, 0.f, 0.f, 0.f};

    // prologue: stage slabs 0,1,2 (12 GLDS in flight); vmcnt(8) -> slab 0 landed
#pragma unroll
    for (int s = 0; s < 3; ++s) {
        GLDS(ap0 + s * 32, &As[s][(size_t)tid * 8]);
        GLDS(ap1 + s * 32, &As[s][(size_t)(512 + tid) * 8]);
        GLDS(bp0 + s * 32, &Bs[s][(size_t)tid * 8]);
        GLDS(bp1 + s * 32, &Bs[s][(size_t)(512 + tid) * 8]);
    }
    VMW(8); SCHED0; BAR;

#pragma unroll 1
    for (int s = 0; s < NKI - 4; s += 4) {   // each iter: slabs s..s+3, staging s+3..s+6
        F_SLAB(0, s + 0, 1, VMW(8));
        F_SLAB(1, s + 1, 1, VMW(8));
        F_SLAB(2, s + 2, 1, VMW(8));
        F_SLAB(3, s + 3, 1, VMW(8));
    }
    // tail: slabs NKI-4..NKI-1 (first stages slab NKI-1; then drain 8 -> 4 -> 0)
    F_SLAB(0, NKI - 4, 1, VMW(8));
    F_SLAB(1, NKI - 3, 0, VMW(4));
    F_SLAB(2, NKI - 2, 0, VMW(0));
    F_SLAB(3, NKI - 1, 0, (void)0);

    // epilogue; C/D layout: col = lane&15, row = (lane>>4)*4 + reg
    int col0 = nt * 256 + wn + (lane & 15);
    int rowq = (lane >> 4) * 4;
    float bv[4];
#pragma unroll
    for (int n = 0; n < 4; ++n) bv[n] = bias[e * N + col0 + n * 16];

#pragma unroll
    for (int m = 0; m < 8; ++m) {
#pragma unroll
        for (int r2 = 0; r2 < 4; ++r2) {
            int lr = wm + m * 16 + rowq + r2;
            if (lr < rows) {
                if (FFN1) {
                    unsigned short* hr = Hout + (size_t)(rowbase + lr) * DF + col0;
#pragma unroll
                    for (int n = 0; n < 4; ++n) {
                        float v = acc[m][n][r2] + bv[n];
                        v = v > 0.f ? v : 0.f;
                        hr[n * 16] = f2bf(v);
                    }
                } else {
                    float* yr = Yout + (size_t)perm[rowbase + lr] * DM + col0;
#pragma unroll
                    for (int n = 0; n < 4; ++n)
                        yr[n * 16] = acc[m][n][r2] + bv[n];
                }
            }
        }
    }
}
#undef F_SLAB

extern "C" void kernel_launch(void* const* d_in, const int* in_sizes, int n_in,
                              void* d_out, int out_size, void* d_ws, size_t ws_size,
                              hipStream_t stream) {
    const float* x  = (const float*)d_in[0];
    const float* w1 = (const float*)d_in[1];
    const float* b1 = (const float*)d_in[2];
    const float* w2 = (const float*)d_in[3];
    const float* b2 = (const float*)d_in[4];
    const float* gw = (const float*)d_in[5];
    const float* gb = (const float*)d_in[6];
    float* out = (float*)d_out;

    // workspace carve-up
    char* ws = (char*)d_ws;
    int* ctrl = (int*)ws;                                   // 2 KiB control block
    int* top1 = (int*)(ws + 2048);                          // 8192 ints
    int* perm = (int*)(ws + 2048 + 32768);                  // 8192 ints
    size_t o = 67584;                                       // 256B-aligned
    unsigned short* xb  = (unsigned short*)(ws + o);        o += (size_t)NTOK * DM * 2;      // 16.8 MB
    unsigned short* w1t = (unsigned short*)(ws + o);        o += (size_t)NE * DM * DF * 2;   // 67 MB
    unsigned short* w2t = (unsigned short*)(ws + o);        o += (size_t)NE * DM * DF * 2;   // 67 MB
    unsigned short* H   = (unsigned short*)(ws + o);        // 67 MB  (total ~218 MB)

    hipMemsetAsync(ctrl, 0, 2048, stream);
    gate_kernel<<<NTOK, 64, 0, stream>>>(x, gw, gb, top1, xb);
    count_kernel<<<NTOK / 256, 256, 0, stream>>>(top1, ctrl);
    prefix_kernel<<<1, 64, 0, stream>>>(ctrl);
    scatter_kernel<<<NTOK / 256, 256, 0, stream>>>(top1, ctrl, perm);
    transpose_both<<<2 * NE * (DM / 64) * (DF / 64), 256, 0, stream>>>(w1, w1t, w2, w2t);
    ffn_gemm<true ><<<MT256 * (DF / 256), 512, 0, stream>>>(xb, w1t, b1, ctrl, perm, H, nullptr);
    ffn_gemm<false><<<MT256 * (DM / 256), 512, 0, stream>>>(H, w2t, b2, ctrl, perm, nullptr, out);
}

// Round 5
// 561.984 us; speedup vs baseline: 1.2112x; 1.0424x over previous
//
#include <hip/hip_runtime.h>
#include <stdint.h>

#define DM 1024
#define DF 4096
#define NE 8
#define NTOK 8192   // B*S = 4*2048
#define MT256 40    // >= max 256-row tiles (39), /8

typedef __attribute__((ext_vector_type(8))) short short8;
typedef __attribute__((ext_vector_type(8))) unsigned short ushort8v;
typedef __attribute__((ext_vector_type(4))) float floatx4;

__device__ inline unsigned short f2bf(float f) {
    union { float f; unsigned u; } v; v.f = f;
    unsigned u = v.u;
    u += 0x7fffu + ((u >> 16) & 1u);   // round-to-nearest-even
    return (unsigned short)(u >> 16);
}

#define GLDS(g, l) __builtin_amdgcn_global_load_lds( \
    (const __attribute__((address_space(1))) void*)(g), \
    (__attribute__((address_space(3))) void*)(l), 16, 0, 0)

#define VMW(N)  asm volatile("s_waitcnt vmcnt(" #N ")" ::: "memory")
#define SCHED0  __builtin_amdgcn_sched_barrier(0)
#define BAR     __builtin_amdgcn_s_barrier()

// ======= fused gate + weight-transpose: one grid, branch on blockIdx =======
// blocks [0, NTOK/4): gating, 4 waves/block, one token per wave, fp64 acc; also emits bf16 x.
// blocks [NTOK/4, ...): tiled transpose+convert w1 then w2: [E][R][C] f32 -> [E][C][R] bf16.
// Co-schedules gate's latency-bound waves under the transpose's BW-bound ones.
__global__ __launch_bounds__(256) void gate_transpose(
    const float* __restrict__ x, const float* __restrict__ gw, const float* __restrict__ gb,
    int* __restrict__ top1, unsigned short* __restrict__ xb,
    const float* __restrict__ w1, unsigned short* __restrict__ w1t,
    const float* __restrict__ w2, unsigned short* __restrict__ w2t) {
    constexpr int GATE_BLKS = NTOK / 4;               // 2048
    constexpr int NT1 = NE * (DM / 64) * (DF / 64);   // 8192 tiles per weight
    __shared__ float tile[64][65];
    int bid = blockIdx.x;
    int tid = threadIdx.x;

    if (bid < GATE_BLKS) {
        int wave = tid >> 6, lane = tid & 63;
        int t = bid * 4 + wave;
        const float* xr = x + (size_t)t * DM;
        unsigned short* xbr = xb + (size_t)t * DM;
        double acc[NE];
#pragma unroll
        for (int e = 0; e < NE; ++e) acc[e] = 0.0;
        for (int j = 0; j < DM / 64; ++j) {
            int d = j * 64 + lane;
            float xf = xr[d];
            xbr[d] = f2bf(xf);
            double xv = (double)xf;
            const float* g = gw + (size_t)d * NE;
#pragma unroll
            for (int e = 0; e < NE; ++e) acc[e] = fma(xv, (double)g[e], acc[e]);
        }
#pragma unroll
        for (int e = 0; e < NE; ++e) {
            for (int off = 32; off > 0; off >>= 1)
                acc[e] += __shfl_down(acc[e], off, 64);
        }
        if (lane == 0) {
            int best = 0;
            double bv = acc[0] + (double)gb[0];
            for (int e = 1; e < NE; ++e) {
                double v = acc[e] + (double)gb[e];
                if (v > bv) { bv = v; best = e; }   // strict > == first-max (jnp.argmax)
            }
            top1[t] = best;
        }
        return;
    }

    bid -= GATE_BLKS;
    const float* src; unsigned short* dst; int R, C;
    if (bid < NT1) { src = w1; dst = w1t; R = DM; C = DF; }
    else           { bid -= NT1; src = w2; dst = w2t; R = DF; C = DM; }
    int tilesR = R >> 6, tilesC = C >> 6;
    int e = bid / (tilesR * tilesC);
    int rem = bid % (tilesR * tilesC);
    int tr = rem / tilesC, tc = rem % tilesC;
    const float* s = src + (size_t)e * R * C + (size_t)(tr * 64) * C + tc * 64;
    unsigned short* d = dst + (size_t)e * R * C + (size_t)(tc * 64) * R + tr * 64;
#pragma unroll
    for (int i = 0; i < 4; ++i) {
        int idx = i * 256 + tid;          // 0..1023
        int r = idx >> 4, c4 = (idx & 15) * 4;
        float4 v = *(const float4*)(s + (size_t)r * C + c4);
        tile[r][c4 + 0] = v.x; tile[r][c4 + 1] = v.y;
        tile[r][c4 + 2] = v.z; tile[r][c4 + 3] = v.w;
    }
    __syncthreads();
#pragma unroll
    for (int i = 0; i < 2; ++i) {
        int idx = i * 256 + tid;          // 0..511
        int c = idx >> 3, r8 = (idx & 7) * 8;
        ushort8v o;
#pragma unroll
        for (int j = 0; j < 8; ++j) o[j] = f2bf(tile[r8 + j][c]);
        *(ushort8v*)(d + (size_t)c * R + r8) = o;
    }
}

// ======= fused count+prefix+scatter+table-build: ONE single-block kernel, LDS state =======
// ctrl ints used downstream: [25] ntiles256, [32+3i..] tile table (expert, rowbase, rows).
// No prior memset needed; all state local. 1024 threads = 16 waves, 8 tokens/thread.
__global__ __launch_bounds__(1024) void sort_kernel(const int* __restrict__ top1,
                                                    int* __restrict__ ctrl,
                                                    int* __restrict__ perm) {
    __shared__ int cnt[NE];
    __shared__ int cur[NE];
    int tid = threadIdx.x, lane = tid & 63;
    if (tid < NE) cnt[tid] = 0;
    __syncthreads();
    int ev[8];
#pragma unroll
    for (int j = 0; j < 8; ++j) ev[j] = top1[j * 1024 + tid];
    // wave-ballot counting, one LDS atomic per (wave, expert)
#pragma unroll
    for (int e = 0; e < NE; ++e) {
        int c = 0;
#pragma unroll
        for (int j = 0; j < 8; ++j) {
            unsigned long long m = __ballot(ev[j] == e);
            c += __popcll(m);
        }
        if (lane == 0) atomicAdd(&cnt[e], c);
    }
    __syncthreads();
    if (tid == 0) {
        int s = 0, t256 = 0;
        for (int e = 0; e < NE; ++e) {
            int c = cnt[e];
            cur[e] = s;
            for (int m = 0; m * 256 < c; ++m) {
                ctrl[32 + 3 * t256] = e;
                ctrl[33 + 3 * t256] = s + m * 256;
                int rr = c - m * 256;
                ctrl[34 + 3 * t256] = rr < 256 ? rr : 256;
                ++t256;
            }
            s += c;
        }
        ctrl[25] = t256;
    }
    __syncthreads();
    // scatter: wave-aggregated LDS cursor bumps (order within expert is arbitrary — OK)
#pragma unroll
    for (int j = 0; j < 8; ++j) {
        int e = ev[j];
#pragma unroll
        for (int ex = 0; ex < NE; ++ex) {
            unsigned long long m = __ballot(e == ex);
            if (m == 0ull) continue;
            int leader = __ffsll((long long)m) - 1;
            int base = 0;
            if (lane == leader) base = atomicAdd(&cur[ex], __popcll(m));
            base = __shfl(base, leader, 64);
            if (e == ex) {
                int pos = __popcll(m & ((1ull << lane) - 1ull));
                perm[base + pos] = j * 1024 + tid;   // compacted position -> token id
            }
        }
    }
}

// ================= FFN GEMM: 256x256 tile, 8 waves, ring-4 BK=32 slabs, counted vmcnt ===========
// LDS slab: [256 rows][4 slots][8 bf16]; slot s' holds global k-chunk s'^((row>>1)&3)
// (pre-swizzled GLOBAL source, linear GLDS dest). Fragment ds_read_b128 -> 2-way banks (free).
// Schedule (T3+T4+T5): stage 3 slabs ahead; ONE s_barrier per slab (32 MFMA/barrier);
// per-wave vmcnt(8) before the slab-end barrier => slab s+1 fully landed after it.
// Ring overwrite safety: slab s+3 -> buf[(s-1)&3], drained before slab s-1's end barrier.
// All ring indices compile-time (x4 unroll + peeled tail); vmcnt ledger counts ONLY the GLDS
// (VMW's "memory" clobber pins GLDS ordering; ds_reads are C-level loads).
// NEW (round 5): no explicit lgkmcnt(0) drain — reads issued in order {bf, af0-3, ag4-7},
// MFMA split into two 16-groups, letting the COMPILER emit fine-grained lgkmcnt(4/3/1/0)
// so group-1 MFMA overlaps the ag reads (its demonstrated strength, m97 asm / G7).
#define F_SLAB(u, SU, STG, W) do { \
    if (STG) { \
        int kk_ = ((SU) + 3) * 32; \
        GLDS(ap0 + kk_, &As[((u) + 3) & 3][(size_t)tid * 8]); \
        GLDS(ap1 + kk_, &As[((u) + 3) & 3][(size_t)(512 + tid) * 8]); \
        GLDS(bp0 + kk_, &Bs[((u) + 3) & 3][(size_t)tid * 8]); \
        GLDS(bp1 + kk_, &Bs[((u) + 3) & 3][(size_t)(512 + tid) * 8]); \
    } \
    short8 bf[4], af[4], ag[4]; \
    _Pragma("unroll") \
    for (int n_ = 0; n_ < 4; ++n_) bf[n_] = *(const short8*)&Bs[u][boff[n_]]; \
    _Pragma("unroll") \
    for (int m_ = 0; m_ < 4; ++m_) af[m_] = *(const short8*)&As[u][aoff[m_]]; \
    _Pragma("unroll") \
    for (int m_ = 0; m_ < 4; ++m_) ag[m_] = *(const short8*)&As[u][aoff[4 + m_]]; \
    __builtin_amdgcn_s_setprio(1); \
    _Pragma("unroll") \
    for (int m_ = 0; m_ < 4; ++m_) \
        _Pragma("unroll") \
        for (int n_ = 0; n_ < 4; ++n_) \
            acc[m_][n_] = __builtin_amdgcn_mfma_f32_16x16x32_bf16(af[m_], bf[n_], acc[m_][n_], 0, 0, 0); \
    _Pragma("unroll") \
    for (int m_ = 0; m_ < 4; ++m_) \
        _Pragma("unroll") \
        for (int n_ = 0; n_ < 4; ++n_) \
            acc[4 + m_][n_] = __builtin_amdgcn_mfma_f32_16x16x32_bf16(ag[m_], bf[n_], acc[4 + m_][n_], 0, 0, 0); \
    __builtin_amdgcn_s_setprio(0); \
    W; SCHED0; BAR; \
} while (0)

template<bool FFN1>
__global__ __launch_bounds__(512, 2) void ffn_gemm(
    const unsigned short* __restrict__ A,    // FFN1: xb [NTOK][DM]; FFN2: H [NTOK][DF] compacted
    const unsigned short* __restrict__ Bt,   // FFN1: w1t [E][DF][DM]; FFN2: w2t [E][DM][DF]
    const float* __restrict__ bias,          // b1 [E][DF] / b2 [E][DM]
    const int* __restrict__ ctrl,
    const int* __restrict__ perm,
    unsigned short* __restrict__ Hout,       // FFN1 out
    float* __restrict__ Yout) {              // FFN2 out
    constexpr int K = FFN1 ? DM : DF;        // 1024 / 4096
    constexpr int N = FFN1 ? DF : DM;        // 4096 / 1024
    constexpr int NT = N / 256;              // 16 / 4
    constexpr int NKI = K / 32;              // 32 / 128
    constexpr int SLABSZ = 256 * 32;         // ushorts (16 KiB)
    constexpr int G = 8;

    // XCD-bijective remap + nt-major group order
    int nwg = gridDim.x;
    int bo = blockIdx.x;
    int q = nwg >> 3, r = nwg & 7;
    int xcd = bo & 7, lid = bo >> 3;
    int b = (xcd < r ? xcd * (q + 1) : r * (q + 1) + (xcd - r) * q) + lid;

    int grp = b / (G * NT);
    int ii = b % (G * NT);
    int nt = ii / G;
    int til = grp * G + (ii % G);
    if (til >= ctrl[25]) return;
    int e       = ctrl[32 + 3 * til];
    int rowbase = ctrl[33 + 3 * til];
    int rows    = ctrl[34 + 3 * til];

    __shared__ __align__(16) unsigned short As[4][SLABSZ];
    __shared__ __align__(16) unsigned short Bs[4][SLABSZ];

    int tid = threadIdx.x, lane = tid & 63, wave = tid >> 6;
    int wm = (wave >> 2) * 128;   // 0 / 128
    int wn = (wave & 3) * 64;     // 0..192

    // staging: each thread stages 2 rows/slab per operand: row tid>>2 and 128+(tid>>2)
    int rA0 = tid >> 2, rA1 = 128 + (tid >> 2);
    int kofs = ((tid & 3) ^ ((tid >> 3) & 3)) * 8;   // pre-swizzled global k-chunk
    int c0 = rowbase + (rA0 < rows ? rA0 : rows - 1);
    int c1 = rowbase + (rA1 < rows ? rA1 : rows - 1);
    const unsigned short* ap0;
    const unsigned short* ap1;
    if (FFN1) {
        ap0 = A + (size_t)perm[c0] * K + kofs;
        ap1 = A + (size_t)perm[c1] * K + kofs;
    } else {
        ap0 = A + (size_t)c0 * K + kofs;
        ap1 = A + (size_t)c1 * K + kofs;
    }
    const unsigned short* bb  = Bt + (size_t)e * N * K + (size_t)(nt * 256) * K + kofs;
    const unsigned short* bp0 = bb + (size_t)rA0 * K;
    const unsigned short* bp1 = bb + (size_t)rA1 * K;

    // fragment LDS offsets (ushort units), constant per lane; chunk g=lane>>4 at slot g^((R>>1)&3)
    int aoff[8], boff[4];
#pragma unroll
    for (int m = 0; m < 8; ++m) {
        int R = wm + m * 16 + (lane & 15);
        aoff[m] = R * 32 + (((lane >> 4) ^ ((R >> 1) & 3)) * 8);
    }
#pragma unroll
    for (int n = 0; n < 4; ++n) {
        int R = wn + n * 16 + (lane & 15);
        boff[n] = R * 32 + (((lane >> 4) ^ ((R >> 1) & 3)) * 8);
    }

    floatx4 acc[8][4];
#pragma unroll
    for (int i = 0; i < 8; ++i)
#pragma unroll
        for (int j = 0; j < 4; ++j) acc[i][j] = floatx4{0.f, 0.f, 0.f, 0.f};

    // prologue: stage slabs 0,1,2 (12 GLDS in flight); vmcnt(8) -> slab 0 landed
#pragma unroll
    for (int s = 0; s < 3; ++s) {
        GLDS(ap0 + s * 32, &As[s][(size_t)tid * 8]);
        GLDS(ap1 + s * 32, &As[s][(size_t)(512 + tid) * 8]);
        GLDS(bp0 + s * 32, &Bs[s][(size_t)tid * 8]);
        GLDS(bp1 + s * 32, &Bs[s][(size_t)(512 + tid) * 8]);
    }
    VMW(8); SCHED0; BAR;

#pragma unroll 1
    for (int s = 0; s < NKI - 4; s += 4) {   // each iter: slabs s..s+3, staging s+3..s+6
        F_SLAB(0, s + 0, 1, VMW(8));
        F_SLAB(1, s + 1, 1, VMW(8));
        F_SLAB(2, s + 2, 1, VMW(8));
        F_SLAB(3, s + 3, 1, VMW(8));
    }
    // tail: slabs NKI-4..NKI-1 (first stages slab NKI-1; then drain 8 -> 4 -> 0)
    F_SLAB(0, NKI - 4, 1, VMW(8));
    F_SLAB(1, NKI - 3, 0, VMW(4));
    F_SLAB(2, NKI - 2, 0, VMW(0));
    F_SLAB(3, NKI - 1, 0, (void)0);

    // epilogue; C/D layout: col = lane&15, row = (lane>>4)*4 + reg
    int col0 = nt * 256 + wn + (lane & 15);
    int rowq = (lane >> 4) * 4;
    float bv[4];
#pragma unroll
    for (int n = 0; n < 4; ++n) bv[n] = bias[e * N + col0 + n * 16];

#pragma unroll
    for (int m = 0; m < 8; ++m) {
#pragma unroll
        for (int r2 = 0; r2 < 4; ++r2) {
            int lr = wm + m * 16 + rowq + r2;
            if (lr < rows) {
                if (FFN1) {
                    unsigned short* hr = Hout + (size_t)(rowbase + lr) * DF + col0;
#pragma unroll
                    for (int n = 0; n < 4; ++n) {
                        float v = acc[m][n][r2] + bv[n];
                        v = v > 0.f ? v : 0.f;
                        hr[n * 16] = f2bf(v);
                    }
                } else {
                    float* yr = Yout + (size_t)perm[rowbase + lr] * DM + col0;
#pragma unroll
                    for (int n = 0; n < 4; ++n)
                        yr[n * 16] = acc[m][n][r2] + bv[n];
                }
            }
        }
    }
}
#undef F_SLAB

extern "C" void kernel_launch(void* const* d_in, const int* in_sizes, int n_in,
                              void* d_out, int out_size, void* d_ws, size_t ws_size,
                              hipStream_t stream) {
    const float* x  = (const float*)d_in[0];
    const float* w1 = (const float*)d_in[1];
    const float* b1 = (const float*)d_in[2];
    const float* w2 = (const float*)d_in[3];
    const float* b2 = (const float*)d_in[4];
    const float* gw = (const float*)d_in[5];
    const float* gb = (const float*)d_in[6];
    float* out = (float*)d_out;

    // workspace carve-up
    char* ws = (char*)d_ws;
    int* ctrl = (int*)ws;                                   // 2 KiB control block
    int* top1 = (int*)(ws + 2048);                          // 8192 ints
    int* perm = (int*)(ws + 2048 + 32768);                  // 8192 ints
    size_t o = 67584;                                       // 256B-aligned
    unsigned short* xb  = (unsigned short*)(ws + o);        o += (size_t)NTOK * DM * 2;      // 16.8 MB
    unsigned short* w1t = (unsigned short*)(ws + o);        o += (size_t)NE * DM * DF * 2;   // 67 MB
    unsigned short* w2t = (unsigned short*)(ws + o);        o += (size_t)NE * DM * DF * 2;   // 67 MB
    unsigned short* H   = (unsigned short*)(ws + o);        // 67 MB  (total ~218 MB)

    // 4 dispatches total (was 9): fused gate+transpose, fused sort, ffn1, ffn2
    gate_transpose<<<NTOK / 4 + 2 * NE * (DM / 64) * (DF / 64), 256, 0, stream>>>(
        x, gw, gb, top1, xb, w1, w1t, w2, w2t);
    sort_kernel<<<1, 1024, 0, stream>>>(top1, ctrl, perm);
    ffn_gemm<true ><<<MT256 * (DF / 256), 512, 0, stream>>>(xb, w1t, b1, ctrl, perm, H, nullptr);
    ffn_gemm<false><<<MT256 * (DM / 256), 512, 0, stream>>>(H, w2t, b2, ctrl, perm, nullptr, out);
}